// Round 4
// baseline (2991.862 us; speedup 1.0000x reference)
//
#include <hip/hip_runtime.h>
#include <cfloat>
#include <math.h>

#define NN 96
#define DIN 16
#define HID 256
#define LAT 128
#define EDGE 4656
#define OUTDIM 6192
#define NT 768            // 12 waves

// ---- LDS float offsets ----
#define XRo   0           // X[96][100] row-major, x[i][a] at i*100+a
#define MRo   9600        // M[97][100]; row 96 = zeros (dummy for padded NBR)
#define SDo   19300       // SD[96][96]: Sdiag[i][a] (built last, scratch overlays first)
// prefix scratch inside SD region (dead before SD is built):
#define T1o   (SDo)          // 1536: t1[96][16]
#define RS1o  (SDo+1536)     // 768
#define RS2o  (SDo+2304)     // 768
#define MUo   (SDo+3072)     // 256
#define INVo  (SDo+3328)     // 256
#define KRo   (SDo+3584)     // 128
#define PZAo  (SDo+3712)     // 512: e11 partials [128][4]
#define PZCo  (SDo+4224)     // 512: e12 partials [128][4]
#define DEGTo 28516
#define DEGRo 28612
#define DRVo  28708
#define GHo   28804       // 256
#define ZSo   29060       // 128
#define H1Do  29188       // 128
#define KLVo  29316       // 1 (+3 pad)
#define WFo   29320       // 2*12 norm^2 partials ping-pong
#define REDo  29344       // 24
#define INDSo 29368       // 96 int
#define CNT4o 29464       // 96 int (cnt rounded up to mult of 4)
#define MSKo  29560       // 96*3 u32
#define NBRo  29848       // u16[96*32] = 1536 floats
#define POOLF 31384       // ~125.5 KB

// ws (global scratch) float offsets
#define WH1   0
#define WX1   24576
#define WT2   49152
#define WH2   73728
#define WOUTP 98304
#define WOUTX 102960
#define WB    104496      // B[96][96]

__device__ __forceinline__ float4 f4add(float4 a, float4 b) {
  return make_float4(a.x + b.x, a.y + b.y, a.z + b.z, a.w + b.w);
}

__global__ __launch_bounds__(NT, 3) void k_all(
    const float* __restrict__ feats, const float* __restrict__ adj,
    const float* __restrict__ w1, const float* __restrict__ w2,
    const float* __restrict__ bn1g, const float* __restrict__ bn1b,
    const float* __restrict__ bn2g, const float* __restrict__ bn2b,
    const float* __restrict__ e11w, const float* __restrict__ e11b,
    const float* __restrict__ e12w, const float* __restrict__ e12b,
    const float* __restrict__ d1w, const float* __restrict__ d1b,
    const float* __restrict__ d2w, const float* __restrict__ d2b,
    const float* __restrict__ eps, float* __restrict__ ws,
    float* __restrict__ out) {
  __shared__ __align__(16) float POOL[POOLF];
  unsigned* MSK = (unsigned*)&POOL[MSKo];
  int* INDS = (int*)&POOL[INDSo];
  int* CNT4 = (int*)&POOL[CNT4o];
  unsigned short* NBR = (unsigned short*)&POOL[NBRo];
  float* h1ws = ws + WH1;
  float* x1ws = ws + WX1;
  float* t2ws = ws + WT2;
  float* h2ws = ws + WH2;
  float* outpws = ws + WOUTP;
  float* outxws = ws + WOUTX;
  float* Bws = ws + WB;

  const int t = threadIdx.x;
  const int w = t >> 6, l = t & 63;

  // ---------- ph1: adjacency bitmasks, degt, neighbor lists (store j*100), M dummy row ----------
  if (t < NN) {
    unsigned m0 = 0, m1 = 0, m2 = 0;
    int cnt = 0;
    float dg = 0.f;
    for (int j = 0; j < NN; ++j) {
      float v = adj[t * NN + j];
      if (v > 0.5f) {
        unsigned bit = 1u << (j & 31);
        if (j < 32) m0 |= bit; else if (j < 64) m1 |= bit; else m2 |= bit;
        dg += 1.f;
        if (j != t && cnt < 32) { NBR[t * 32 + cnt] = (unsigned short)(j * 100); ++cnt; }
      }
    }
    MSK[t * 3 + 0] = m0; MSK[t * 3 + 1] = m1; MSK[t * 3 + 2] = m2;
    POOL[DEGTo + t] = dg;
    int c4 = (cnt + 3) & ~3;
    for (int k = cnt; k < c4; ++k) NBR[t * 32 + k] = (unsigned short)9600; // dummy zero row
    CNT4[t] = c4;
  }
  if (t < 100) POOL[MRo + 9600 + t] = 0.f;   // M dummy row = 0
  __syncthreads();

  // ---------- ph2: t1 = adj @ feats (masked sums incl diagonal) ----------
  for (int o = t; o < NN * DIN; o += NT) {
    int i = o >> 4, k = o & 15;
    float s = 0.f;
    for (int wd = 0; wd < 3; ++wd) {
      unsigned mw = MSK[i * 3 + wd];
      while (mw) { int jb = __builtin_ctz(mw); mw &= mw - 1; s += feats[(wd * 32 + jb) * DIN + k]; }
    }
    POOL[T1o + o] = s;
  }
  __syncthreads();

  // ---------- ph3: h1 = t1 @ w1 ---------- (c = t&255, q = t>>8 in [0,3): 32 rows each)
  {
    int c = t & 255, q = t >> 8;
    float acc[32];
#pragma unroll
    for (int i = 0; i < 32; ++i) acc[i] = 0.f;
    for (int k = 0; k < DIN; k += 4) {
      float wv0 = w1[k * HID + c], wv1 = w1[(k + 1) * HID + c];
      float wv2 = w1[(k + 2) * HID + c], wv3 = w1[(k + 3) * HID + c];
#pragma unroll
      for (int i = 0; i < 32; ++i) {
        float4 tv = *(const float4*)&POOL[T1o + (q * 32 + i) * DIN + k];
        acc[i] = fmaf(tv.x, wv0, fmaf(tv.y, wv1, fmaf(tv.z, wv2, fmaf(tv.w, wv3, acc[i]))));
      }
    }
#pragma unroll
    for (int i = 0; i < 32; ++i) h1ws[(q * 32 + i) * HID + c] = acc[i];
  }
  __syncthreads();

  // ---------- ph4: bn1 + relu -> x1 ----------
  {
    int c = t & 255, q = t >> 8;
    float s1 = 0.f, s2 = 0.f;
    for (int i = q * 32; i < q * 32 + 32; ++i) { float v = h1ws[i * HID + c]; s1 += v; s2 += v * v; }
    POOL[RS1o + q * 256 + c] = s1; POOL[RS2o + q * 256 + c] = s2;
  }
  __syncthreads();
  if (t < 256) {
    float s1 = POOL[RS1o + t] + POOL[RS1o + 256 + t] + POOL[RS1o + 512 + t];
    float s2 = POOL[RS2o + t] + POOL[RS2o + 256 + t] + POOL[RS2o + 512 + t];
    float mu = s1 / 96.f;
    float var = s2 / 96.f - mu * mu;
    POOL[MUo + t] = mu; POOL[INVo + t] = rsqrtf(var + 1e-5f);
  }
  __syncthreads();
  {
    int c = t & 255, q = t >> 8;
    float mu = POOL[MUo + c], iv = POOL[INVo + c], g = bn1g[c], b = bn1b[c];
    for (int i = q * 32; i < q * 32 + 32; ++i) {
      float v = h1ws[i * HID + c];
      x1ws[i * HID + c] = fmaxf((v - mu) * iv * g + b, 0.f);
    }
  }
  __syncthreads();

  // ---------- ph5: t2 = adj @ x1 (masked sums) ----------
  for (int o = t; o < NN * HID; o += NT) {
    int i = o >> 8, c = o & 255;
    float s = 0.f;
    for (int wd = 0; wd < 3; ++wd) {
      unsigned mw = MSK[i * 3 + wd];
      while (mw) { int jb = __builtin_ctz(mw); mw &= mw - 1; s += x1ws[(wd * 32 + jb) * HID + c]; }
    }
    t2ws[o] = s;
  }
  __syncthreads();

  // ---------- ph6: h2 = t2 @ w2 ----------
  {
    int c = t & 255, q = t >> 8;
    float acc[32];
#pragma unroll
    for (int i = 0; i < 32; ++i) acc[i] = 0.f;
    for (int k = 0; k < HID; k += 4) {
      float wv0 = w2[k * HID + c], wv1 = w2[(k + 1) * HID + c];
      float wv2 = w2[(k + 2) * HID + c], wv3 = w2[(k + 3) * HID + c];
#pragma unroll
      for (int i = 0; i < 32; ++i) {
        float4 tv = *(const float4*)&t2ws[(q * 32 + i) * HID + k];
        acc[i] = fmaf(tv.x, wv0, fmaf(tv.y, wv1, fmaf(tv.z, wv2, fmaf(tv.w, wv3, acc[i]))));
      }
    }
#pragma unroll
    for (int i = 0; i < 32; ++i) h2ws[(q * 32 + i) * HID + c] = acc[i];
  }
  __syncthreads();

  // ---------- ph7: bn2 stats + gh ----------
  {
    int c = t & 255, q = t >> 8;
    float s1 = 0.f, s2 = 0.f;
    for (int i = q * 32; i < q * 32 + 32; ++i) { float v = h2ws[i * HID + c]; s1 += v; s2 += v * v; }
    POOL[RS1o + q * 256 + c] = s1; POOL[RS2o + q * 256 + c] = s2;
  }
  __syncthreads();
  if (t < 256) {
    float s1 = POOL[RS1o + t] + POOL[RS1o + 256 + t] + POOL[RS1o + 512 + t];
    float s2 = POOL[RS2o + t] + POOL[RS2o + 256 + t] + POOL[RS2o + 512 + t];
    float mu = s1 / 96.f;
    float var = s2 / 96.f - mu * mu;
    POOL[MUo + t] = mu; POOL[INVo + t] = rsqrtf(var + 1e-5f);
  }
  __syncthreads();
  {
    int c = t & 255, q = t >> 8;
    float mu = POOL[MUo + c], iv = POOL[INVo + c], g = bn2g[c], b = bn2b[c];
    float s = 0.f;
    for (int i = q * 32; i < q * 32 + 32; ++i) {
      float v = h2ws[i * HID + c];
      s += (v - mu) * iv * g + b;
    }
    POOL[RS1o + q * 256 + c] = s;
  }
  __syncthreads();
  if (t < 256)
    POOL[GHo + t] = POOL[RS1o + t] + POOL[RS1o + 256 + t] + POOL[RS1o + 512 + t];
  __syncthreads();

  // ---------- ph8: VAE heads (parallel partials: 512 threads) ----------
  if (t < 512) {
    int r = t & 127, part = t >> 7;           // part in [0,4), 64 k each
    float a = 0.f, c = 0.f;
    for (int k = part * 64; k < part * 64 + 64; ++k) {
      float g = POOL[GHo + k];
      a = fmaf(e11w[r * HID + k], g, a);
      c = fmaf(e12w[r * HID + k], g, c);
    }
    POOL[PZAo + r * 4 + part] = a;
    POOL[PZCo + r * 4 + part] = c;
  }
  __syncthreads();
  if (t < LAT) {
    float a = e11b[t] + POOL[PZAo + t * 4] + POOL[PZAo + t * 4 + 1] + POOL[PZAo + t * 4 + 2] + POOL[PZAo + t * 4 + 3];
    float c = e12b[t] + POOL[PZCo + t * 4] + POOL[PZCo + t * 4 + 1] + POOL[PZCo + t * 4 + 2] + POOL[PZCo + t * 4 + 3];
    POOL[ZSo + t] = eps[t] * expf(0.5f * c) + a;
    POOL[KRo + t] = 1.f + c - a * a - expf(c);
  }
  __syncthreads();
  if (t == 0) {
    float s = 0.f;
    for (int k = 0; k < 128; ++k) s += POOL[KRo + k];
    POOL[KLVo] = -0.5f * s / (96.f * 96.f);
  }
  // ---------- ph9: h1d = relu(d1w @ z + d1b) (parallel partials) ----------
  if (t < 512) {
    int r = t & 127, part = t >> 7;           // 32 k each
    float hv = 0.f;
    for (int k = part * 32; k < part * 32 + 32; ++k)
      hv = fmaf(d1w[r * LAT + k], POOL[ZSo + k], hv);
    POOL[PZAo + r * 4 + part] = hv;
  }
  __syncthreads();
  if (t < LAT) {
    float hv = d1b[t] + POOL[PZAo + t * 4] + POOL[PZAo + t * 4 + 1] + POOL[PZAo + t * 4 + 2] + POOL[PZAo + t * 4 + 3];
    POOL[H1Do + t] = fmaxf(hv, 0.f);
  }
  __syncthreads();

  // ---------- ph10: decoder ----------
  for (int o = t; o < OUTDIM; o += NT) {
    const float4* wr = (const float4*)(d2w + o * LAT);
    float s = d2b[o];
    for (int k4 = 0; k4 < 32; ++k4) {
      float4 v = wr[k4];
      const float* hz = &POOL[H1Do + k4 * 4];
      s = fmaf(v.x, hz[0], fmaf(v.y, hz[1], fmaf(v.z, hz[2], fmaf(v.w, hz[3], s))));
    }
    if (o < EDGE) outpws[o] = 1.f / (1.f + expf(-s));
    else outxws[o - EDGE] = s;
  }
  __syncthreads();

  // ---------- ph11: degr, dr ----------
  if (t < NN) {
    float s = 0.f;
    for (int b = 0; b < NN; ++b) {
      int i2 = min(t, b), j2 = max(t, b);
      int e = i2 * NN - (i2 * (i2 - 1)) / 2 + (j2 - i2);
      s += outpws[e];
    }
    POOL[DEGRo + t] = s;
    int ed = t * NN - (t * (t - 1)) / 2;
    POOL[DRVo + t] = outpws[ed];
  }
  __syncthreads();

  // ---------- ph12: B (global), SD, X init ----------
  for (int o = t; o < NN * NN; o += NT) {
    int a = o / NN, b = o - a * NN;
    float v = 0.f;
    if (a != b) {
      int i2 = min(a, b), j2 = max(a, b);
      int e = i2 * NN - (i2 * (i2 - 1)) / 2 + (j2 - i2);
      v = outpws[e] * POOL[DRVo + a] * POOL[DRVo + b];
    }
    Bws[o] = v;                                  // B[a][b]
  }
  for (int o = t; o < NN * NN; o += NT) {
    int i = o / NN, a = o - i * NN;
    POOL[SDo + o] = POOL[DRVo + a] / (fabsf(POOL[DEGTo + i] - POOL[DEGRo + a]) + 1.f);
  }
  for (int o = t; o < 9600; o += NT) POOL[XRo + o] = 1.f / 96.f;
  __syncthreads();

  // ---------- load this lane's B row into registers (persists across MPM) ----------
  const int arow = (w < 8) ? l : 64 + (l & 31);
  const int jbase = (w < 8) ? 12 * w : 24 * (w - 8) + 12 * (l >> 5);
  float4 Breg[24];
  {
    const float4* bg = (const float4*)(Bws + arow * NN);
#pragma unroll
    for (int q = 0; q < 24; ++q) Breg[q] = bg[q];
  }

  // ---------- MPM: 50 iterations ----------
  const int si = t >> 3, saq = t & 7;            // sum phase: i, quad-base
  const int sc4 = CNT4[si];
#pragma unroll 1
  for (int m = 0; m < 50; ++m) {
    // ---- max phase: M[j][a] = max_b B[a][b]*x[j][b]; B in regs, x broadcast ----
#pragma unroll 1
    for (int jj = 0; jj < 12; ++jj) {
      int j = jbase + jj;
      const float4* xr = (const float4*)&POOL[XRo + j * 100];
      float mA = 0.f, mB = 0.f;
#pragma unroll
      for (int q = 0; q < 12; ++q) {
        float4 x0 = xr[2 * q], x1 = xr[2 * q + 1];
        float4 b0 = Breg[2 * q], b1 = Breg[2 * q + 1];
        mA = fmaxf(mA, fmaxf(b0.x * x0.x, b0.y * x0.y));
        mA = fmaxf(mA, fmaxf(b0.z * x0.z, b0.w * x0.w));
        mB = fmaxf(mB, fmaxf(b1.x * x1.x, b1.y * x1.y));
        mB = fmaxf(mB, fmaxf(b1.z * x1.z, b1.w * x1.w));
      }
      POOL[MRo + j * 100 + arow] = fmaxf(mA, mB);
    }
    __syncthreads();

    // ---- sum phase: xn[i][a] = (x[i][a]*Sd[i][a] + sum_{j in N(i)} M[j][a]) * inv ----
    float inv = 1.f;
    if (m > 0) {
      int pp = ((m & 1) ^ 1) * 12;
      float sv = 0.f;
#pragma unroll
      for (int q = 0; q < 12; ++q) sv += POOL[WFo + pp + q];
      inv = rsqrtf(sv);
    }
    float4 acc0 = make_float4(0.f, 0.f, 0.f, 0.f);
    float4 acc1 = acc0, acc2 = acc0;
    {
      const ushort2* nb2 = (const ushort2*)(NBR + si * 32);
      int trips = sc4 >> 1;
#pragma unroll 1
      for (int e2 = 0; e2 < trips; ++e2) {
        ushort2 jj2 = nb2[e2];
        const float* r0 = &POOL[MRo + jj2.x + 4 * saq];
        const float* r1 = &POOL[MRo + jj2.y + 4 * saq];
        float4 v00 = *(const float4*)r0;
        float4 v01 = *(const float4*)(r0 + 32);
        float4 v02 = *(const float4*)(r0 + 64);
        float4 v10 = *(const float4*)r1;
        float4 v11 = *(const float4*)(r1 + 32);
        float4 v12 = *(const float4*)(r1 + 64);
        acc0 = f4add(acc0, f4add(v00, v10));
        acc1 = f4add(acc1, f4add(v01, v11));
        acc2 = f4add(acc2, f4add(v02, v12));
      }
    }
    float ss = 0.f;
    {
      float4 accs[3] = {acc0, acc1, acc2};
#pragma unroll
      for (int s = 0; s < 3; ++s) {
        int aoff = 4 * (saq + 8 * s);
        float4 xq = *(const float4*)&POOL[XRo + si * 100 + aoff];
        float4 sd = *(const float4*)&POOL[SDo + si * 96 + aoff];
        float4 v;
        v.x = (xq.x * sd.x + accs[s].x) * inv;
        v.y = (xq.y * sd.y + accs[s].y) * inv;
        v.z = (xq.z * sd.z + accs[s].z) * inv;
        v.w = (xq.w * sd.w + accs[s].w) * inv;
        *(float4*)&POOL[XRo + si * 100 + aoff] = v;
        ss += v.x * v.x + v.y * v.y + v.z * v.z + v.w * v.w;
      }
    }
#pragma unroll
    for (int off = 32; off >= 1; off >>= 1) ss += __shfl_xor(ss, off);
    if (l == 0) POOL[WFo + (m & 1) * 12 + w] = ss;
    __syncthreads();
  }

  // ---------- greedy assignment (wave 0; exact first-index tie-break) ----------
  if (w == 0) {
    float mA = -1.f, mB = -1.f; int aA = 0, aB = 0;
    bool alA = true, alB = (l < 32);
    for (int c = 0; c < NN; ++c) { float v = POOL[XRo + l * 100 + c]; if (v > mA) { mA = v; aA = c; } }
    if (l < 32) for (int c = 0; c < NN; ++c) { float v = POOL[XRo + (64 + l) * 100 + c]; if (v > mB) { mB = v; aB = c; } }
    unsigned long long colm0 = ~0ull;
    unsigned long long colm1 = 0xFFFFFFFFull;
    for (int step = 0; step < NN; ++step) {
      unsigned long long kA = alA
        ? ((((unsigned long long)__float_as_uint(mA)) << 32) | (unsigned)(0x3FFF - (l * NN + aA))) : 0ull;
      unsigned long long kB = alB
        ? ((((unsigned long long)__float_as_uint(mB)) << 32) | (unsigned)(0x3FFF - ((64 + l) * NN + aB))) : 0ull;
      unsigned long long kk = kA > kB ? kA : kB;
#pragma unroll
      for (int off = 1; off < 64; off <<= 1) {
        unsigned long long o = __shfl_xor(kk, off);
        if (o > kk) kk = o;
      }
      int flat = 0x3FFF - (int)(kk & 0xFFFFFFFFull);
      int r = flat / NN, c = flat - (flat / NN) * NN;
      if (l == 0) INDS[c] = r;
      if (c < 64) colm0 &= ~(1ull << c); else colm1 &= ~(1ull << (c - 64));
      if (l == r) alA = false;
      if (alB && (64 + l) == r) alB = false;
      if (alA && aA == c) {
        mA = -1.f; aA = 0;
        unsigned long long mm0 = colm0;
        while (mm0) { int c2 = __builtin_ctzll(mm0); mm0 &= mm0 - 1; float v = POOL[XRo + l * 100 + c2]; if (v > mA) { mA = v; aA = c2; } }
        unsigned long long mm1 = colm1;
        while (mm1) { int c2 = 64 + __builtin_ctzll(mm1); mm1 &= mm1 - 1; float v = POOL[XRo + l * 100 + c2]; if (v > mA) { mA = v; aA = c2; } }
      }
      if (alB && aB == c) {
        mB = -1.f; aB = 0;
        unsigned long long mm0 = colm0;
        while (mm0) { int c2 = __builtin_ctzll(mm0); mm0 &= mm0 - 1; float v = POOL[XRo + (64 + l) * 100 + c2]; if (v > mB) { mB = v; aB = c2; } }
        unsigned long long mm1 = colm1;
        while (mm1) { int c2 = 64 + __builtin_ctzll(mm1); mm1 &= mm1 - 1; float v = POOL[XRo + (64 + l) * 100 + c2]; if (v > mB) { mB = v; aB = c2; } }
      }
    }
  }
  __syncthreads();

  // ---------- losses ----------
  float accf = 0.f;
  for (int p = t; p < NN * DIN; p += NT) {
    int i = p >> 4, k = p & 15;
    float d = outxws[p] - feats[INDS[i] * DIN + k];
    accf += d * d;
  }
  float accb = 0.f;
  for (int e = t; e < EDGE; e += NT) {
    int i = (int)((193.0f - sqrtf(193.0f * 193.0f - 8.0f * (float)e)) * 0.5f);
    if (i < 0) i = 0; if (i > 95) i = 95;
    while (i < 95 && (i + 1) * NN - ((i + 1) * i) / 2 <= e) ++i;
    while (i > 0 && i * NN - (i * (i - 1)) / 2 > e) --i;
    int j = i + (e - (i * NN - (i * (i - 1)) / 2));
    int ri = INDS[i], rj = INDS[j];
    float tv = (float)((MSK[ri * 3 + (rj >> 5)] >> (rj & 31)) & 1u);
    float pr = outpws[e];
    float l1 = fmaxf(logf(pr), -100.f);
    float l0 = fmaxf(log1pf(-pr), -100.f);
    accb += tv * l1 + (1.f - tv) * l0;
  }
#pragma unroll
  for (int off = 32; off >= 1; off >>= 1) { accf += __shfl_xor(accf, off); accb += __shfl_xor(accb, off); }
  if (l == 0) { POOL[REDo + w] = accf; POOL[REDo + 12 + w] = accb; }
  __syncthreads();
  if (t == 0) {
    float ff = 0.f, bb = 0.f;
    for (int q2 = 0; q2 < 12; ++q2) { ff += POOL[REDo + q2]; bb += POOL[REDo + 12 + q2]; }
    out[0] = (-bb / (float)EDGE) + POOL[KLVo] + ff / (float)(NN * DIN);
  }
}

extern "C" void kernel_launch(void* const* d_in, const int* in_sizes, int n_in,
                              void* d_out, int out_size, void* d_ws, size_t ws_size,
                              hipStream_t stream) {
  const float* feats = (const float*)d_in[0];
  const float* adj   = (const float*)d_in[1];
  const float* w1    = (const float*)d_in[2];
  const float* w2    = (const float*)d_in[3];
  const float* bn1g  = (const float*)d_in[4];
  const float* bn1b  = (const float*)d_in[5];
  const float* bn2g  = (const float*)d_in[6];
  const float* bn2b  = (const float*)d_in[7];
  const float* e11w  = (const float*)d_in[8];
  const float* e11b  = (const float*)d_in[9];
  const float* e12w  = (const float*)d_in[10];
  const float* e12b  = (const float*)d_in[11];
  const float* d1w   = (const float*)d_in[12];
  const float* d1b   = (const float*)d_in[13];
  const float* d2w   = (const float*)d_in[14];
  const float* d2b   = (const float*)d_in[15];
  const float* eps   = (const float*)d_in[16];

  k_all<<<1, NT, 0, stream>>>(feats, adj, w1, w2, bn1g, bn1b, bn2g, bn2b,
                              e11w, e11b, e12w, e12b, d1w, d1b, d2w, d2b,
                              eps, (float*)d_ws, (float*)d_out);
}

// Round 5
// 1929.429 us; speedup vs baseline: 1.5506x; 1.5506x over previous
//
#include <hip/hip_runtime.h>
#include <cfloat>
#include <math.h>

#define NN 96
#define DIN 16
#define HID 256
#define LAT 128
#define EDGE 4656
#define OUTDIM 6192
#define NT 768            // 12 waves

// ---- LDS float offsets ----
#define XRo   0           // X[96][100] row-major, x[i][a] at i*100+a
#define MRo   9600        // M[97][100]; row 96 = zeros (dummy for padded NBR)
#define SDo   19300       // SD[96][96]: Sdiag[i][a] (built last, scratch overlays first)
// prefix scratch inside SD region (dead before SD is built):
#define T1o   (SDo)          // 1536: t1[96][16]
#define RS1o  (SDo+1536)     // 768
#define RS2o  (SDo+2304)     // 768
#define MUo   (SDo+3072)     // 256
#define INVo  (SDo+3328)     // 256
#define KRo   (SDo+3584)     // 128
#define PZAo  (SDo+3712)     // 512: e11 partials [128][4]
#define PZCo  (SDo+4224)     // 512: e12 partials [128][4]
#define DEGTo 28516
#define DEGRo 28612
#define DRVo  28708
#define GHo   28804       // 256
#define ZSo   29060       // 128
#define H1Do  29188       // 128
#define KLVo  29316       // 1 (+3 pad)
#define WFo   29320       // 2*12 norm^2 partials ping-pong (16B aligned)
#define REDo  29344       // 24
#define INDSo 29368       // 96 int
#define CNT4o 29464       // 96 int (cnt rounded up to mult of 4)
#define MSKo  29560       // 96*3 u32
#define NBRo  29848       // u16[96*32] = 1536 floats
#define POOLF 31384       // ~125.5 KB

// ws (global scratch) float offsets
#define WH1   0
#define WX1   24576
#define WT2   49152
#define WH2   73728
#define WOUTP 98304
#define WOUTX 102960
#define WB    104496      // B[96][96]

#define GMAX(B_, X_) fmaxf(fmaxf((B_).x*(X_).x, (B_).y*(X_).y), fmaxf((B_).z*(X_).z, (B_).w*(X_).w))

__global__ __launch_bounds__(NT, 1) void k_all(
    const float* __restrict__ feats, const float* __restrict__ adj,
    const float* __restrict__ w1, const float* __restrict__ w2,
    const float* __restrict__ bn1g, const float* __restrict__ bn1b,
    const float* __restrict__ bn2g, const float* __restrict__ bn2b,
    const float* __restrict__ e11w, const float* __restrict__ e11b,
    const float* __restrict__ e12w, const float* __restrict__ e12b,
    const float* __restrict__ d1w, const float* __restrict__ d1b,
    const float* __restrict__ d2w, const float* __restrict__ d2b,
    const float* __restrict__ eps, float* __restrict__ ws,
    float* __restrict__ out) {
  __shared__ __align__(16) float POOL[POOLF];
  unsigned* MSK = (unsigned*)&POOL[MSKo];
  int* INDS = (int*)&POOL[INDSo];
  int* CNT4 = (int*)&POOL[CNT4o];
  unsigned short* NBR = (unsigned short*)&POOL[NBRo];
  float* h1ws = ws + WH1;
  float* x1ws = ws + WX1;
  float* t2ws = ws + WT2;
  float* h2ws = ws + WH2;
  float* outpws = ws + WOUTP;
  float* outxws = ws + WOUTX;
  float* Bws = ws + WB;

  const int t = threadIdx.x;
  const int w = t >> 6, l = t & 63;

  // ---------- ph1: adjacency bitmasks, degt, neighbor lists (store j*100), M dummy row ----------
  if (t < NN) {
    unsigned m0 = 0, m1 = 0, m2 = 0;
    int cnt = 0;
    float dg = 0.f;
    for (int j = 0; j < NN; ++j) {
      float v = adj[t * NN + j];
      if (v > 0.5f) {
        unsigned bit = 1u << (j & 31);
        if (j < 32) m0 |= bit; else if (j < 64) m1 |= bit; else m2 |= bit;
        dg += 1.f;
        if (j != t && cnt < 32) { NBR[t * 32 + cnt] = (unsigned short)(j * 100); ++cnt; }
      }
    }
    MSK[t * 3 + 0] = m0; MSK[t * 3 + 1] = m1; MSK[t * 3 + 2] = m2;
    POOL[DEGTo + t] = dg;
    int c4 = (cnt + 3) & ~3;
    for (int k = cnt; k < c4; ++k) NBR[t * 32 + k] = (unsigned short)9600; // dummy zero row
    CNT4[t] = c4;
  }
  if (t < 100) POOL[MRo + 9600 + t] = 0.f;   // M dummy row = 0
  __syncthreads();

  // ---------- ph2: t1 = adj @ feats (masked sums incl diagonal) ----------
  for (int o = t; o < NN * DIN; o += NT) {
    int i = o >> 4, k = o & 15;
    float s = 0.f;
    for (int wd = 0; wd < 3; ++wd) {
      unsigned mw = MSK[i * 3 + wd];
      while (mw) { int jb = __builtin_ctz(mw); mw &= mw - 1; s += feats[(wd * 32 + jb) * DIN + k]; }
    }
    POOL[T1o + o] = s;
  }
  __syncthreads();

  // ---------- ph3: h1 = t1 @ w1 ----------
  {
    int c = t & 255, q = t >> 8;
    float acc[32];
#pragma unroll
    for (int i = 0; i < 32; ++i) acc[i] = 0.f;
    for (int k = 0; k < DIN; k += 4) {
      float wv0 = w1[k * HID + c], wv1 = w1[(k + 1) * HID + c];
      float wv2 = w1[(k + 2) * HID + c], wv3 = w1[(k + 3) * HID + c];
#pragma unroll
      for (int i = 0; i < 32; ++i) {
        float4 tv = *(const float4*)&POOL[T1o + (q * 32 + i) * DIN + k];
        acc[i] = fmaf(tv.x, wv0, fmaf(tv.y, wv1, fmaf(tv.z, wv2, fmaf(tv.w, wv3, acc[i]))));
      }
    }
#pragma unroll
    for (int i = 0; i < 32; ++i) h1ws[(q * 32 + i) * HID + c] = acc[i];
  }
  __syncthreads();

  // ---------- ph4: bn1 + relu -> x1 ----------
  {
    int c = t & 255, q = t >> 8;
    float s1 = 0.f, s2 = 0.f;
    for (int i = q * 32; i < q * 32 + 32; ++i) { float v = h1ws[i * HID + c]; s1 += v; s2 += v * v; }
    POOL[RS1o + q * 256 + c] = s1; POOL[RS2o + q * 256 + c] = s2;
  }
  __syncthreads();
  if (t < 256) {
    float s1 = POOL[RS1o + t] + POOL[RS1o + 256 + t] + POOL[RS1o + 512 + t];
    float s2 = POOL[RS2o + t] + POOL[RS2o + 256 + t] + POOL[RS2o + 512 + t];
    float mu = s1 / 96.f;
    float var = s2 / 96.f - mu * mu;
    POOL[MUo + t] = mu; POOL[INVo + t] = rsqrtf(var + 1e-5f);
  }
  __syncthreads();
  {
    int c = t & 255, q = t >> 8;
    float mu = POOL[MUo + c], iv = POOL[INVo + c], g = bn1g[c], b = bn1b[c];
    for (int i = q * 32; i < q * 32 + 32; ++i) {
      float v = h1ws[i * HID + c];
      x1ws[i * HID + c] = fmaxf((v - mu) * iv * g + b, 0.f);
    }
  }
  __syncthreads();

  // ---------- ph5: t2 = adj @ x1 (masked sums) ----------
  for (int o = t; o < NN * HID; o += NT) {
    int i = o >> 8, c = o & 255;
    float s = 0.f;
    for (int wd = 0; wd < 3; ++wd) {
      unsigned mw = MSK[i * 3 + wd];
      while (mw) { int jb = __builtin_ctz(mw); mw &= mw - 1; s += x1ws[(wd * 32 + jb) * HID + c]; }
    }
    t2ws[o] = s;
  }
  __syncthreads();

  // ---------- ph6: h2 = t2 @ w2 ----------
  {
    int c = t & 255, q = t >> 8;
    float acc[32];
#pragma unroll
    for (int i = 0; i < 32; ++i) acc[i] = 0.f;
    for (int k = 0; k < HID; k += 4) {
      float wv0 = w2[k * HID + c], wv1 = w2[(k + 1) * HID + c];
      float wv2 = w2[(k + 2) * HID + c], wv3 = w2[(k + 3) * HID + c];
#pragma unroll
      for (int i = 0; i < 32; ++i) {
        float4 tv = *(const float4*)&t2ws[(q * 32 + i) * HID + k];
        acc[i] = fmaf(tv.x, wv0, fmaf(tv.y, wv1, fmaf(tv.z, wv2, fmaf(tv.w, wv3, acc[i]))));
      }
    }
#pragma unroll
    for (int i = 0; i < 32; ++i) h2ws[(q * 32 + i) * HID + c] = acc[i];
  }
  __syncthreads();

  // ---------- ph7: bn2 stats + gh ----------
  {
    int c = t & 255, q = t >> 8;
    float s1 = 0.f, s2 = 0.f;
    for (int i = q * 32; i < q * 32 + 32; ++i) { float v = h2ws[i * HID + c]; s1 += v; s2 += v * v; }
    POOL[RS1o + q * 256 + c] = s1; POOL[RS2o + q * 256 + c] = s2;
  }
  __syncthreads();
  if (t < 256) {
    float s1 = POOL[RS1o + t] + POOL[RS1o + 256 + t] + POOL[RS1o + 512 + t];
    float s2 = POOL[RS2o + t] + POOL[RS2o + 256 + t] + POOL[RS2o + 512 + t];
    float mu = s1 / 96.f;
    float var = s2 / 96.f - mu * mu;
    POOL[MUo + t] = mu; POOL[INVo + t] = rsqrtf(var + 1e-5f);
  }
  __syncthreads();
  {
    int c = t & 255, q = t >> 8;
    float mu = POOL[MUo + c], iv = POOL[INVo + c], g = bn2g[c], b = bn2b[c];
    float s = 0.f;
    for (int i = q * 32; i < q * 32 + 32; ++i) {
      float v = h2ws[i * HID + c];
      s += (v - mu) * iv * g + b;
    }
    POOL[RS1o + q * 256 + c] = s;
  }
  __syncthreads();
  if (t < 256)
    POOL[GHo + t] = POOL[RS1o + t] + POOL[RS1o + 256 + t] + POOL[RS1o + 512 + t];
  __syncthreads();

  // ---------- ph8: VAE heads (parallel partials: 512 threads) ----------
  if (t < 512) {
    int r = t & 127, part = t >> 7;
    float a = 0.f, c = 0.f;
    for (int k = part * 64; k < part * 64 + 64; ++k) {
      float g = POOL[GHo + k];
      a = fmaf(e11w[r * HID + k], g, a);
      c = fmaf(e12w[r * HID + k], g, c);
    }
    POOL[PZAo + r * 4 + part] = a;
    POOL[PZCo + r * 4 + part] = c;
  }
  __syncthreads();
  if (t < LAT) {
    float a = e11b[t] + POOL[PZAo + t * 4] + POOL[PZAo + t * 4 + 1] + POOL[PZAo + t * 4 + 2] + POOL[PZAo + t * 4 + 3];
    float c = e12b[t] + POOL[PZCo + t * 4] + POOL[PZCo + t * 4 + 1] + POOL[PZCo + t * 4 + 2] + POOL[PZCo + t * 4 + 3];
    POOL[ZSo + t] = eps[t] * expf(0.5f * c) + a;
    POOL[KRo + t] = 1.f + c - a * a - expf(c);
  }
  __syncthreads();
  if (t == 0) {
    float s = 0.f;
    for (int k = 0; k < 128; ++k) s += POOL[KRo + k];
    POOL[KLVo] = -0.5f * s / (96.f * 96.f);
  }
  // ---------- ph9: h1d = relu(d1w @ z + d1b) ----------
  if (t < 512) {
    int r = t & 127, part = t >> 7;
    float hv = 0.f;
    for (int k = part * 32; k < part * 32 + 32; ++k)
      hv = fmaf(d1w[r * LAT + k], POOL[ZSo + k], hv);
    POOL[PZAo + r * 4 + part] = hv;
  }
  __syncthreads();
  if (t < LAT) {
    float hv = d1b[t] + POOL[PZAo + t * 4] + POOL[PZAo + t * 4 + 1] + POOL[PZAo + t * 4 + 2] + POOL[PZAo + t * 4 + 3];
    POOL[H1Do + t] = fmaxf(hv, 0.f);
  }
  __syncthreads();

  // ---------- ph10: decoder ----------
  for (int o = t; o < OUTDIM; o += NT) {
    const float4* wr = (const float4*)(d2w + o * LAT);
    float s = d2b[o];
    for (int k4 = 0; k4 < 32; ++k4) {
      float4 v = wr[k4];
      const float* hz = &POOL[H1Do + k4 * 4];
      s = fmaf(v.x, hz[0], fmaf(v.y, hz[1], fmaf(v.z, hz[2], fmaf(v.w, hz[3], s))));
    }
    if (o < EDGE) outpws[o] = 1.f / (1.f + expf(-s));
    else outxws[o - EDGE] = s;
  }
  __syncthreads();

  // ---------- ph11: degr, dr ----------
  if (t < NN) {
    float s = 0.f;
    for (int b = 0; b < NN; ++b) {
      int i2 = min(t, b), j2 = max(t, b);
      int e = i2 * NN - (i2 * (i2 - 1)) / 2 + (j2 - i2);
      s += outpws[e];
    }
    POOL[DEGRo + t] = s;
    int ed = t * NN - (t * (t - 1)) / 2;
    POOL[DRVo + t] = outpws[ed];
  }
  __syncthreads();

  // ---------- ph12: B (global), SD, X init ----------
  for (int o = t; o < NN * NN; o += NT) {
    int a = o / NN, b = o - a * NN;
    float v = 0.f;
    if (a != b) {
      int i2 = min(a, b), j2 = max(a, b);
      int e = i2 * NN - (i2 * (i2 - 1)) / 2 + (j2 - i2);
      v = outpws[e] * POOL[DRVo + a] * POOL[DRVo + b];
    }
    Bws[o] = v;                                  // B[a][b]
  }
  for (int o = t; o < NN * NN; o += NT) {
    int i = o / NN, a = o - i * NN;
    POOL[SDo + o] = POOL[DRVo + a] / (fabsf(POOL[DEGTo + i] - POOL[DEGRo + a]) + 1.f);
  }
  for (int o = t; o < 9600; o += NT) POOL[XRo + o] = 1.f / 96.f;
  __syncthreads();

  // ---------- B half-row into 12 NAMED float4 registers (persists across MPM) ----------
  // wave w: jset = w/3 handles j in [24*jset, 24*jset+24); wsub = w%3 covers a-block of 32.
  // lane: a = wsub*32 + (l>>1), half h = l&1 covers b in [48h, 48h+48).
  const int jset = w / 3, wsub = w - jset * 3;
  const int amax = wsub * 32 + (l >> 1);
  const int hh = l & 1;
  float4 Bq0, Bq1, Bq2, Bq3, Bq4, Bq5, Bq6, Bq7, Bq8, Bq9, Bq10, Bq11;
  {
    const float4* bg = (const float4*)(Bws + amax * NN + hh * 48);
    Bq0 = bg[0];  Bq1 = bg[1];  Bq2 = bg[2];  Bq3 = bg[3];
    Bq4 = bg[4];  Bq5 = bg[5];  Bq6 = bg[6];  Bq7 = bg[7];
    Bq8 = bg[8];  Bq9 = bg[9];  Bq10 = bg[10]; Bq11 = bg[11];
  }

  // sum-phase lane mapping: lane owns (a-quad ag, i-block ib of 3 rows)
  const int ag4 = 4 * (t % 24);
  const int ib = t / 24;

  // ---------- MPM: 50 iterations ----------
#pragma unroll 1
  for (int m = 0; m < 50; ++m) {
    // ---- max phase: M[j][a] = max_b B[a][b]*x[j][b] ----
#pragma unroll 2
    for (int jj = 0; jj < 24; ++jj) {
      const int j = jset * 24 + jj;
      const float4* xr = (const float4*)&POOL[XRo + j * 100 + hh * 48];
      float4 x0 = xr[0], x1 = xr[1], x2 = xr[2], x3 = xr[3];
      float4 x4 = xr[4], x5 = xr[5], x6 = xr[6], x7 = xr[7];
      float4 x8 = xr[8], x9 = xr[9], x10 = xr[10], x11 = xr[11];
      float mA = GMAX(Bq0, x0), mB = GMAX(Bq1, x1);
      mA = fmaxf(mA, GMAX(Bq2, x2));  mB = fmaxf(mB, GMAX(Bq3, x3));
      mA = fmaxf(mA, GMAX(Bq4, x4));  mB = fmaxf(mB, GMAX(Bq5, x5));
      mA = fmaxf(mA, GMAX(Bq6, x6));  mB = fmaxf(mB, GMAX(Bq7, x7));
      mA = fmaxf(mA, GMAX(Bq8, x8));  mB = fmaxf(mB, GMAX(Bq9, x9));
      mA = fmaxf(mA, GMAX(Bq10, x10)); mB = fmaxf(mB, GMAX(Bq11, x11));
      float mm = fmaxf(mA, mB);
      mm = fmaxf(mm, __shfl_xor(mm, 1));
      if (hh == 0) POOL[MRo + j * 100 + amax] = mm;
    }
    __syncthreads();

    // ---- sum phase: xn[i][a] = (x[i][a]*Sd[i][a] + sum_{j in N(i)} M[j][a]) * inv ----
    float inv = 1.f;
    if (m > 0) {
      const float* wp = &POOL[WFo + ((m & 1) ^ 1) * 12];
      float4 a0 = *(const float4*)wp;
      float4 a1 = *(const float4*)(wp + 4);
      float4 a2 = *(const float4*)(wp + 8);
      inv = rsqrtf(a0.x + a0.y + a0.z + a0.w + a1.x + a1.y + a1.z + a1.w +
                   a2.x + a2.y + a2.z + a2.w);
    }
    float ss = 0.f;
#pragma unroll
    for (int q = 0; q < 3; ++q) {
      const int i = ib * 3 + q;
      const ushort2* nb = (const ushort2*)(NBR + i * 32);
      const int pr = CNT4[i] >> 1;
      float4 acc = make_float4(0.f, 0.f, 0.f, 0.f);
#pragma unroll 2
      for (int e = 0; e < pr; ++e) {
        ushort2 jj2 = nb[e];
        float4 va = *(const float4*)&POOL[MRo + jj2.x + ag4];
        float4 vb = *(const float4*)&POOL[MRo + jj2.y + ag4];
        acc.x += va.x + vb.x; acc.y += va.y + vb.y;
        acc.z += va.z + vb.z; acc.w += va.w + vb.w;
      }
      float4 xq = *(const float4*)&POOL[XRo + i * 100 + ag4];
      float4 sd = *(const float4*)&POOL[SDo + i * 96 + ag4];
      float4 v;
      v.x = fmaf(xq.x, sd.x, acc.x) * inv;
      v.y = fmaf(xq.y, sd.y, acc.y) * inv;
      v.z = fmaf(xq.z, sd.z, acc.z) * inv;
      v.w = fmaf(xq.w, sd.w, acc.w) * inv;
      *(float4*)&POOL[XRo + i * 100 + ag4] = v;
      ss += v.x * v.x + v.y * v.y + v.z * v.z + v.w * v.w;
    }
#pragma unroll
    for (int off = 32; off >= 1; off >>= 1) ss += __shfl_xor(ss, off);
    if (l == 0) POOL[WFo + (m & 1) * 12 + w] = ss;
    __syncthreads();
  }

  // ---------- greedy assignment (wave 0; exact first-index tie-break) ----------
  if (w == 0) {
    float mA = -1.f, mB = -1.f; int aA = 0, aB = 0;
    bool alA = true, alB = (l < 32);
    for (int c = 0; c < NN; ++c) { float v = POOL[XRo + l * 100 + c]; if (v > mA) { mA = v; aA = c; } }
    if (l < 32) for (int c = 0; c < NN; ++c) { float v = POOL[XRo + (64 + l) * 100 + c]; if (v > mB) { mB = v; aB = c; } }
    unsigned long long colm0 = ~0ull;
    unsigned long long colm1 = 0xFFFFFFFFull;
    for (int step = 0; step < NN; ++step) {
      unsigned long long kA = alA
        ? ((((unsigned long long)__float_as_uint(mA)) << 32) | (unsigned)(0x3FFF - (l * NN + aA))) : 0ull;
      unsigned long long kB = alB
        ? ((((unsigned long long)__float_as_uint(mB)) << 32) | (unsigned)(0x3FFF - ((64 + l) * NN + aB))) : 0ull;
      unsigned long long kk = kA > kB ? kA : kB;
#pragma unroll
      for (int off = 1; off < 64; off <<= 1) {
        unsigned long long o = __shfl_xor(kk, off);
        if (o > kk) kk = o;
      }
      int flat = 0x3FFF - (int)(kk & 0xFFFFFFFFull);
      int r = flat / NN, c = flat - (flat / NN) * NN;
      if (l == 0) INDS[c] = r;
      if (c < 64) colm0 &= ~(1ull << c); else colm1 &= ~(1ull << (c - 64));
      if (l == r) alA = false;
      if (alB && (64 + l) == r) alB = false;
      if (alA && aA == c) {
        mA = -1.f; aA = 0;
        unsigned long long mm0 = colm0;
        while (mm0) { int c2 = __builtin_ctzll(mm0); mm0 &= mm0 - 1; float v = POOL[XRo + l * 100 + c2]; if (v > mA) { mA = v; aA = c2; } }
        unsigned long long mm1 = colm1;
        while (mm1) { int c2 = 64 + __builtin_ctzll(mm1); mm1 &= mm1 - 1; float v = POOL[XRo + l * 100 + c2]; if (v > mA) { mA = v; aA = c2; } }
      }
      if (alB && aB == c) {
        mB = -1.f; aB = 0;
        unsigned long long mm0 = colm0;
        while (mm0) { int c2 = __builtin_ctzll(mm0); mm0 &= mm0 - 1; float v = POOL[XRo + (64 + l) * 100 + c2]; if (v > mB) { mB = v; aB = c2; } }
        unsigned long long mm1 = colm1;
        while (mm1) { int c2 = 64 + __builtin_ctzll(mm1); mm1 &= mm1 - 1; float v = POOL[XRo + (64 + l) * 100 + c2]; if (v > mB) { mB = v; aB = c2; } }
      }
    }
  }
  __syncthreads();

  // ---------- losses ----------
  float accf = 0.f;
  for (int p = t; p < NN * DIN; p += NT) {
    int i = p >> 4, k = p & 15;
    float d = outxws[p] - feats[INDS[i] * DIN + k];
    accf += d * d;
  }
  float accb = 0.f;
  for (int e = t; e < EDGE; e += NT) {
    int i = (int)((193.0f - sqrtf(193.0f * 193.0f - 8.0f * (float)e)) * 0.5f);
    if (i < 0) i = 0; if (i > 95) i = 95;
    while (i < 95 && (i + 1) * NN - ((i + 1) * i) / 2 <= e) ++i;
    while (i > 0 && i * NN - (i * (i - 1)) / 2 > e) --i;
    int j = i + (e - (i * NN - (i * (i - 1)) / 2));
    int ri = INDS[i], rj = INDS[j];
    float tv = (float)((MSK[ri * 3 + (rj >> 5)] >> (rj & 31)) & 1u);
    float pr = outpws[e];
    float l1 = fmaxf(logf(pr), -100.f);
    float l0 = fmaxf(log1pf(-pr), -100.f);
    accb += tv * l1 + (1.f - tv) * l0;
  }
#pragma unroll
  for (int off = 32; off >= 1; off >>= 1) { accf += __shfl_xor(accf, off); accb += __shfl_xor(accb, off); }
  if (l == 0) { POOL[REDo + w] = accf; POOL[REDo + 12 + w] = accb; }
  __syncthreads();
  if (t == 0) {
    float ff = 0.f, bb = 0.f;
    for (int q2 = 0; q2 < 12; ++q2) { ff += POOL[REDo + q2]; bb += POOL[REDo + 12 + q2]; }
    out[0] = (-bb / (float)EDGE) + POOL[KLVo] + ff / (float)(NN * DIN);
  }
}

extern "C" void kernel_launch(void* const* d_in, const int* in_sizes, int n_in,
                              void* d_out, int out_size, void* d_ws, size_t ws_size,
                              hipStream_t stream) {
  const float* feats = (const float*)d_in[0];
  const float* adj   = (const float*)d_in[1];
  const float* w1    = (const float*)d_in[2];
  const float* w2    = (const float*)d_in[3];
  const float* bn1g  = (const float*)d_in[4];
  const float* bn1b  = (const float*)d_in[5];
  const float* bn2g  = (const float*)d_in[6];
  const float* bn2b  = (const float*)d_in[7];
  const float* e11w  = (const float*)d_in[8];
  const float* e11b  = (const float*)d_in[9];
  const float* e12w  = (const float*)d_in[10];
  const float* e12b  = (const float*)d_in[11];
  const float* d1w   = (const float*)d_in[12];
  const float* d1b   = (const float*)d_in[13];
  const float* d2w   = (const float*)d_in[14];
  const float* d2b   = (const float*)d_in[15];
  const float* eps   = (const float*)d_in[16];

  k_all<<<1, NT, 0, stream>>>(feats, adj, w1, w2, bn1g, bn1b, bn2g, bn2b,
                              e11w, e11b, e12w, e12b, d1w, d1b, d2w, d2b,
                              eps, (float*)d_ws, (float*)d_out);
}

// Round 6
// 1043.374 us; speedup vs baseline: 2.8675x; 1.8492x over previous
//
#include <hip/hip_runtime.h>
#include <cfloat>
#include <math.h>

#define N 96
#define DIN 16
#define HID 256
#define LAT 128
#define EDGE 4656
#define OUTDIM 6192

typedef unsigned long long ull;

// ---- ws float offsets ----
enum {
  WH1   = 0,            // 96*256
  WX1   = 24576,        // 96*256
  WH2   = 49152,        // 96*256
  WGH   = 73728,        // 256
  WKL   = 73984,        // 4
  WOUTP = 73988,        // 4656
  WOUTX = 78644,        // 1536
  WDEGT = 80180,        // 96
  WDEGR = 80276,        // 96
  WDT   = 80372,        // 96
  WDR   = 80468,        // 96
  WB    = 80564,        // 96*96
  WSDT  = 89780,        // 96*96  SdT[a][i]
  WMSK  = 98996,        // 192 ull = 384 floats (8B aligned)
  WXA   = 99380,        // 96*104 row-major padded
  WXB   = 109364,       // 96*104
  WXAT  = 119348,       // 96*96  col-major (xT[a][i] = x[i][a])
  WXBT  = 128564,       // 96*96
  WSSP  = 137780        // 2*96
};

__device__ __forceinline__ int triidx(int i, int j) { // requires i<=j
  return i * N - (i * (i - 1)) / 2 + (j - i);
}

// ---- h1 = (adj @ feats) @ conv1_w ; block=row i, 256 thr ----
__global__ void k_enc1(const float* __restrict__ adj, const float* __restrict__ feats,
                       const float* __restrict__ w1, float* __restrict__ h1) {
  int i = blockIdx.x, t = threadIdx.x;
  __shared__ float p[16][17];
  __shared__ float t1[16];
  int k = t & 15, part = t >> 4;
  float s = 0.f;
  for (int j = part * 6; j < part * 6 + 6; ++j) s += adj[i * N + j] * feats[j * DIN + k];
  p[part][k] = s;
  __syncthreads();
  if (t < 16) { float q = 0.f; for (int r = 0; r < 16; ++r) q += p[r][t]; t1[t] = q; }
  __syncthreads();
  float h = 0.f;
  for (int kk = 0; kk < 16; ++kk) h += t1[kk] * w1[kk * HID + t];
  h1[i * HID + t] = h;
}

// ---- BN1 + ReLU ; block=col c, 128 thr ----
__global__ void k_bn1(const float* __restrict__ h1, const float* __restrict__ gg,
                      const float* __restrict__ bb, float* __restrict__ x1) {
  int c = blockIdx.x, t = threadIdx.x;
  float v = (t < N) ? h1[t * HID + c] : 0.f;
  __shared__ float s1[128], s2[128];
  s1[t] = v; s2[t] = v * v; __syncthreads();
  for (int s = 64; s > 0; s >>= 1) { if (t < s) { s1[t] += s1[t + s]; s2[t] += s2[t + s]; } __syncthreads(); }
  float mu = s1[0] / (float)N;
  float var = s2[0] / (float)N - mu * mu;
  float inv = rsqrtf(var + 1e-5f);
  if (t < N) x1[t * HID + c] = fmaxf((v - mu) * inv * gg[c] + bb[c], 0.f);
}

// ---- h2 = (adj @ x1) @ conv2_w ; block=row i, 256 thr ----
__global__ void k_enc2(const float* __restrict__ adj, const float* __restrict__ x1,
                       const float* __restrict__ w2, float* __restrict__ h2) {
  int i = blockIdx.x, t = threadIdx.x;
  __shared__ float t2[HID];
  float s = 0.f;
  for (int j = 0; j < N; ++j) s += adj[i * N + j] * x1[j * HID + t];
  t2[t] = s;
  __syncthreads();
  float h = 0.f;
  for (int k = 0; k < HID; ++k) h += t2[k] * w2[k * HID + t];
  h2[i * HID + t] = h;
}

// ---- BN2 then gh = column sums ; block=col c ----
__global__ void k_bn2gh(const float* __restrict__ h2, const float* __restrict__ gg,
                        const float* __restrict__ bb, float* __restrict__ gh) {
  int c = blockIdx.x, t = threadIdx.x;
  float v = (t < N) ? h2[t * HID + c] : 0.f;
  __shared__ float s1[128], s2[128];
  s1[t] = v; s2[t] = v * v; __syncthreads();
  for (int s = 64; s > 0; s >>= 1) { if (t < s) { s1[t] += s1[t + s]; s2[t] += s2[t + s]; } __syncthreads(); }
  float mu = s1[0] / (float)N;
  float var = s2[0] / (float)N - mu * mu;
  float inv = rsqrtf(var + 1e-5f);
  __syncthreads();
  float xv = (t < N) ? ((v - mu) * inv * gg[c] + bb[c]) : 0.f;
  s1[t] = xv; __syncthreads();
  for (int s = 64; s > 0; s >>= 1) { if (t < s) s1[t] += s1[t + s]; __syncthreads(); }
  if (t == 0) gh[c] = s1[0];
}

// ---- VAE (redundant per block) + decoder ; 25 blocks x 256 thr ----
__global__ void k_vaedec(const float* __restrict__ gh,
                         const float* __restrict__ e11w, const float* __restrict__ e11b,
                         const float* __restrict__ e12w, const float* __restrict__ e12b,
                         const float* __restrict__ d1w, const float* __restrict__ d1b,
                         const float* __restrict__ d2w, const float* __restrict__ d2b,
                         const float* __restrict__ eps, float* __restrict__ kl,
                         float* __restrict__ outp, float* __restrict__ outx) {
  int t = threadIdx.x;
  __shared__ float ghs[HID], zs[LAT], h1d[LAT], kr[LAT];
  ghs[t] = gh[t];
  __syncthreads();
  if (t < LAT) {
    float a = e11b[t], c = e12b[t];
    for (int k = 0; k < HID; ++k) {
      float g = ghs[k];
      a = fmaf(e11w[t * HID + k], g, a);
      c = fmaf(e12w[t * HID + k], g, c);
    }
    zs[t] = eps[t] * expf(0.5f * c) + a;
    kr[t] = 1.f + c - a * a - expf(c);
  }
  __syncthreads();
  if (blockIdx.x == 0 && t == 0) {
    float s = 0.f;
    for (int k = 0; k < LAT; ++k) s += kr[k];
    kl[0] = -0.5f * s / (float)(N * N);
  }
  if (t < LAT) {
    float hv = d1b[t];
    for (int k = 0; k < LAT; ++k) hv = fmaf(d1w[t * LAT + k], zs[k], hv);
    h1d[t] = fmaxf(hv, 0.f);
  }
  __syncthreads();
  int o = blockIdx.x * 256 + t;
  if (o < OUTDIM) {
    const float4* wr = (const float4*)(d2w + o * LAT);
    float s = d2b[o];
    for (int k4 = 0; k4 < 32; ++k4) {
      float4 v = wr[k4];
      s = fmaf(v.x, h1d[k4 * 4], fmaf(v.y, h1d[k4 * 4 + 1],
            fmaf(v.z, h1d[k4 * 4 + 2], fmaf(v.w, h1d[k4 * 4 + 3], s))));
    }
    if (o < EDGE) outp[o] = 1.f / (1.f + expf(-s));
    else outx[o - EDGE] = s;
  }
}

// ---- degrees, diagonals, adjacency bitmasks ; block=row a, 128 thr ----
__global__ void k_recon(const float* __restrict__ adj, const float* __restrict__ outp,
                        float* __restrict__ degt, float* __restrict__ degr,
                        float* __restrict__ dt, float* __restrict__ dr,
                        ull* __restrict__ mskg) {
  int a = blockIdx.x, t = threadIdx.x;
  float rv = 0.f, av = 0.f;
  if (t < N) {
    int i2 = min(a, t), j2 = max(a, t);
    rv = outp[triidx(i2, j2)];
    av = adj[a * N + t];
    if (t == a) { dr[a] = rv; dt[a] = av; }
  }
  ull bal = __ballot(t < N && av > 0.5f);
  if ((t & 63) == 0) mskg[a * 2 + (t >> 6)] = bal;
  __shared__ float s1[128], s2[128];
  s1[t] = rv; s2[t] = av; __syncthreads();
  for (int s = 64; s > 0; s >>= 1) { if (t < s) { s1[t] += s1[t + s]; s2[t] += s2[t + s]; } __syncthreads(); }
  if (t == 0) { degr[a] = s1[0]; degt[a] = s2[0]; }
}

// ---- B rows, SdT rows, x0 (both layouts) ; block=row a, 128 thr ----
__global__ void k_simab(const float* __restrict__ outp,
                        const float* __restrict__ degt, const float* __restrict__ degr,
                        const float* __restrict__ dt, const float* __restrict__ dr,
                        float* __restrict__ Bg, float* __restrict__ SdTg,
                        float* __restrict__ x0, float* __restrict__ x0T) {
  int a = blockIdx.x, t = threadIdx.x;
  if (t < N) {
    int i2 = min(a, t), j2 = max(a, t);
    float rv = outp[triidx(i2, j2)];
    Bg[a * N + t] = (t == a) ? 0.f : rv * dr[a] * dr[t];
    SdTg[a * N + t] = dt[t] * dr[a] / (fabsf(degt[t] - degr[a]) + 1.f);
    x0[t * 104 + a] = 1.f / (float)N;
    x0T[a * N + t] = 1.f / (float)N;
  }
}

// ---- one MPM iteration ; block = column a, 128 thr (one row per thread) ----
// M[j] = max_b B[a][b]*x[j][b] ;  xn[i][a] = (x[i][a]*Sd[a][i] + sum_{j in N(i)\i} M[j]) * inv
__global__ __launch_bounds__(128) void k_mpm(
    const float* __restrict__ xin,  const float* __restrict__ xinT,
    float* __restrict__ xout, float* __restrict__ xoutT,
    const float* __restrict__ Bg, const float* __restrict__ SdTg,
    const ull* __restrict__ mskg,
    const float* __restrict__ sspP, float* __restrict__ sspC, int first) {
  const int a = blockIdx.x, t = threadIdx.x;
  const int w = t >> 6, l = t & 63;
  __shared__ __align__(16) float Bs[96];
  __shared__ float Sd[96], Xold[96], Ms[96], Xnew[96];
  __shared__ float red[2], red2[2];
  const bool act = (t < N);
  if (act) {
    Bs[t] = Bg[a * N + t];
    Sd[t] = SdTg[a * N + t];
    Xold[t] = xinT[a * N + t];
  }
  // prev-norm^2 reduction (wave shuffle + 2-way LDS combine)
  float sv = (!first && act) ? sspP[t] : 0.f;
#pragma unroll
  for (int off = 32; off >= 1; off >>= 1) sv += __shfl_xor(sv, off);
  if (l == 0) red[w] = sv;
  // self adjacency mask
  ull w0 = 0, w1 = 0;
  if (act) {
    w0 = mskg[t * 2];
    w1 = mskg[t * 2 + 1];
    if (t < 64) w0 &= ~(1ull << t); else w1 &= ~(1ull << (t - 64));
  }
  __syncthreads();
  const float inv = first ? 1.f : rsqrtf(red[0] + red[1]);
  // max phase: thread t owns row j=t
  if (act) {
    const float4* xr = (const float4*)(xin + t * 104);
    const float4* Bs4 = (const float4*)Bs;
    float m0 = 0.f;
#pragma unroll
    for (int k = 0; k < 24; ++k) {
      float4 xq = xr[k];
      float4 bq = Bs4[k];
      m0 = fmaxf(m0, fmaxf(fmaxf(bq.x * xq.x, bq.y * xq.y),
                           fmaxf(bq.z * xq.z, bq.w * xq.w)));
    }
    Ms[t] = m0;
  }
  __syncthreads();
  // sum phase: thread t owns row i=t
  float ss = 0.f;
  if (act) {
    float macc = 0.f;
    ull mm = w0;
    while (mm) { int j = __builtin_ctzll(mm); mm &= mm - 1; macc += Ms[j]; }
    mm = w1;
    while (mm) { int j = 64 + __builtin_ctzll(mm); mm &= mm - 1; macc += Ms[j]; }
    float v = fmaf(Xold[t], Sd[t], macc) * inv;
    Xnew[t] = v;
    xout[t * 104 + a] = v;
    ss = v * v;
  }
#pragma unroll
  for (int off = 32; off >= 1; off >>= 1) ss += __shfl_xor(ss, off);
  if (l == 0) red2[w] = ss;
  __syncthreads();
  if (t == 0) sspC[a] = red2[0] + red2[1];
  if (t < 24) {
    float4 q = *(const float4*)&Xnew[4 * t];
    *(float4*)&xoutT[a * N + 4 * t] = q;
  }
}

// ---- greedy assignment (wave 0) + losses ; 1 block x 256 thr ----
__global__ __launch_bounds__(256) void k_fin(
    const float* __restrict__ xfin,      // [96][104] row-major
    const float* __restrict__ adj, const float* __restrict__ feats,
    const float* __restrict__ outp, const float* __restrict__ outx,
    const float* __restrict__ kl, float* __restrict__ out) {
  int t = threadIdx.x;
  int w = t >> 6, l = t & 63;
  __shared__ float X[96 * 100];
  __shared__ int INDS[96];
  __shared__ float rf[4], rb[4];
  for (int e = t; e < N * N; e += 256) {
    int i = e / N, j = e - i * N;
    X[i * 100 + j] = xfin[i * 104 + j];
  }
  __syncthreads();

  if (w == 0) {
    float mA = -1.f, mB = -1.f; int aA = 0, aB = 0;
    bool alA = true, alB = (l < 32);
    for (int c = 0; c < N; ++c) { float v = X[l * 100 + c]; if (v > mA) { mA = v; aA = c; } }
    if (l < 32) for (int c = 0; c < N; ++c) { float v = X[(64 + l) * 100 + c]; if (v > mB) { mB = v; aB = c; } }
    ull colm0 = ~0ull;
    ull colm1 = 0xFFFFFFFFull;
    for (int step = 0; step < N; ++step) {
      ull kA = alA ? ((((ull)__float_as_uint(mA)) << 32) | (unsigned)(0x3FFF - (l * N + aA))) : 0ull;
      ull kB = alB ? ((((ull)__float_as_uint(mB)) << 32) | (unsigned)(0x3FFF - ((64 + l) * N + aB))) : 0ull;
      ull kk = kA > kB ? kA : kB;
#pragma unroll
      for (int off = 1; off < 64; off <<= 1) {
        ull o = __shfl_xor(kk, off);
        if (o > kk) kk = o;
      }
      int flat = 0x3FFF - (int)(kk & 0xFFFFFFFFull);
      int r = flat / N, c = flat - (flat / N) * N;
      if (l == 0) INDS[c] = r;
      if (c < 64) colm0 &= ~(1ull << c); else colm1 &= ~(1ull << (c - 64));
      if (l == r) alA = false;
      if (alB && (64 + l) == r) alB = false;
      if (alA && aA == c) {
        mA = -1.f; aA = 0;
        ull mm0 = colm0;
        while (mm0) { int c2 = __builtin_ctzll(mm0); mm0 &= mm0 - 1; float v = X[l * 100 + c2]; if (v > mA) { mA = v; aA = c2; } }
        ull mm1 = colm1;
        while (mm1) { int c2 = 64 + __builtin_ctzll(mm1); mm1 &= mm1 - 1; float v = X[l * 100 + c2]; if (v > mA) { mA = v; aA = c2; } }
      }
      if (alB && aB == c) {
        mB = -1.f; aB = 0;
        ull mm0 = colm0;
        while (mm0) { int c2 = __builtin_ctzll(mm0); mm0 &= mm0 - 1; float v = X[(64 + l) * 100 + c2]; if (v > mB) { mB = v; aB = c2; } }
        ull mm1 = colm1;
        while (mm1) { int c2 = 64 + __builtin_ctzll(mm1); mm1 &= mm1 - 1; float v = X[(64 + l) * 100 + c2]; if (v > mB) { mB = v; aB = c2; } }
      }
    }
  }
  __syncthreads();

  float accf = 0.f;
  for (int p = t; p < N * DIN; p += 256) {
    int i = p >> 4, k = p & 15;
    float d = outx[p] - feats[INDS[i] * DIN + k];
    accf += d * d;
  }
  float accb = 0.f;
  for (int i = 0; i < N; ++i) {
    int basee = triidx(i, i);
    int rowlen = N - i;
    for (int jq = t; jq < rowlen; jq += 256) {
      int j = i + jq;
      float tv = adj[INDS[i] * N + INDS[j]];
      float pr = outp[basee + jq];
      float l1 = fmaxf(logf(pr), -100.f);
      float l0 = fmaxf(log1pf(-pr), -100.f);
      accb += tv * l1 + (1.f - tv) * l0;
    }
  }
#pragma unroll
  for (int off = 32; off >= 1; off >>= 1) { accf += __shfl_xor(accf, off); accb += __shfl_xor(accb, off); }
  if (l == 0) { rf[w] = accf; rb[w] = accb; }
  __syncthreads();
  if (t == 0) {
    float ff = rf[0] + rf[1] + rf[2] + rf[3];
    float bb = rb[0] + rb[1] + rb[2] + rb[3];
    out[0] = (-bb / (float)EDGE) + kl[0] + ff / (float)(N * DIN);
  }
}

extern "C" void kernel_launch(void* const* d_in, const int* in_sizes, int n_in,
                              void* d_out, int out_size, void* d_ws, size_t ws_size,
                              hipStream_t stream) {
  const float* feats = (const float*)d_in[0];
  const float* adj   = (const float*)d_in[1];
  const float* w1    = (const float*)d_in[2];
  const float* w2    = (const float*)d_in[3];
  const float* bn1g  = (const float*)d_in[4];
  const float* bn1b  = (const float*)d_in[5];
  const float* bn2g  = (const float*)d_in[6];
  const float* bn2b  = (const float*)d_in[7];
  const float* e11w  = (const float*)d_in[8];
  const float* e11b  = (const float*)d_in[9];
  const float* e12w  = (const float*)d_in[10];
  const float* e12b  = (const float*)d_in[11];
  const float* d1w   = (const float*)d_in[12];
  const float* d1b   = (const float*)d_in[13];
  const float* d2w   = (const float*)d_in[14];
  const float* d2b   = (const float*)d_in[15];
  const float* eps   = (const float*)d_in[16];

  float* ws   = (float*)d_ws;
  float* h1   = ws + WH1;
  float* x1   = ws + WX1;
  float* h2   = ws + WH2;
  float* gh   = ws + WGH;
  float* kl   = ws + WKL;
  float* outp = ws + WOUTP;
  float* outx = ws + WOUTX;
  float* degt = ws + WDEGT;
  float* degr = ws + WDEGR;
  float* dt   = ws + WDT;
  float* dr   = ws + WDR;
  float* Bg   = ws + WB;
  float* SdTg = ws + WSDT;
  ull*   mskg = (ull*)(ws + WMSK);
  float* xa   = ws + WXA;
  float* xb   = ws + WXB;
  float* xaT  = ws + WXAT;
  float* xbT  = ws + WXBT;
  float* ssp  = ws + WSSP;
  float* out  = (float*)d_out;

  k_enc1<<<96, 256, 0, stream>>>(adj, feats, w1, h1);
  k_bn1<<<256, 128, 0, stream>>>(h1, bn1g, bn1b, x1);
  k_enc2<<<96, 256, 0, stream>>>(adj, x1, w2, h2);
  k_bn2gh<<<256, 128, 0, stream>>>(h2, bn2g, bn2b, gh);
  k_vaedec<<<25, 256, 0, stream>>>(gh, e11w, e11b, e12w, e12b, d1w, d1b,
                                   d2w, d2b, eps, kl, outp, outx);
  k_recon<<<96, 128, 0, stream>>>(adj, outp, degt, degr, dt, dr, mskg);
  k_simab<<<96, 128, 0, stream>>>(outp, degt, degr, dt, dr, Bg, SdTg, xa, xaT);

  for (int m = 0; m < 50; ++m) {
    const float* xi  = (m & 1) ? xb : xa;
    const float* xiT = (m & 1) ? xbT : xaT;
    float* xo        = (m & 1) ? xa : xb;
    float* xoT       = (m & 1) ? xaT : xbT;
    float* sc        = ssp + (m & 1) * N;
    const float* sp  = ssp + ((m & 1) ^ 1) * N;
    k_mpm<<<96, 128, 0, stream>>>(xi, xiT, xo, xoT, Bg, SdTg, mskg, sp, sc,
                                  (m == 0) ? 1 : 0);
  }
  // m=49 odd -> final x in xa
  k_fin<<<1, 256, 0, stream>>>(xa, adj, feats, outp, outx, kl, out);
}

// Round 7
// 586.468 us; speedup vs baseline: 5.1015x; 1.7791x over previous
//
#include <hip/hip_runtime.h>
#include <cfloat>
#include <math.h>

#define N 96
#define DIN 16
#define HID 256
#define LAT 128
#define EDGE 4656
#define OUTDIM 6192

typedef unsigned long long ull;

// ---- ws float offsets ----
enum {
  WH1   = 0,            // 96*256
  WX1   = 24576,        // 96*256
  WH2   = 49152,        // 96*256
  WGH   = 73728,        // 256
  WKL   = 73984,        // 4
  WOUTP = 73988,        // 4656
  WOUTX = 78644,        // 1536
  WDEGT = 80180,        // 96
  WDEGR = 80276,        // 96
  WDT   = 80372,        // 96
  WDR   = 80468,        // 96
  WB    = 80564,        // 96*96
  WSDT  = 89780,        // 96*96  SdT[a][i]
  WMSK  = 98996,        // 192 ull = 384 floats (8B aligned)
  WXA   = 99380,        // 96*104 row-major padded
  WXB   = 109364,       // 96*104
  WXAT  = 119348,       // 96*96  col-major (xT[a][i] = x[i][a])
  WXBT  = 128564,       // 96*96
  WSSP  = 137780        // 2*96
};

__device__ __forceinline__ int triidx(int i, int j) { // requires i<=j
  return i * N - (i * (i - 1)) / 2 + (j - i);
}

// ---- h1 = (adj @ feats) @ conv1_w ; block=row i, 256 thr ----
__global__ void k_enc1(const float* __restrict__ adj, const float* __restrict__ feats,
                       const float* __restrict__ w1, float* __restrict__ h1) {
  int i = blockIdx.x, t = threadIdx.x;
  __shared__ float p[16][17];
  __shared__ float t1[16];
  int k = t & 15, part = t >> 4;
  float s = 0.f;
  for (int j = part * 6; j < part * 6 + 6; ++j) s += adj[i * N + j] * feats[j * DIN + k];
  p[part][k] = s;
  __syncthreads();
  if (t < 16) { float q = 0.f; for (int r = 0; r < 16; ++r) q += p[r][t]; t1[t] = q; }
  __syncthreads();
  float h = 0.f;
  for (int kk = 0; kk < 16; ++kk) h += t1[kk] * w1[kk * HID + t];
  h1[i * HID + t] = h;
}

// ---- BN1 + ReLU ; block=col c, 128 thr ----
__global__ void k_bn1(const float* __restrict__ h1, const float* __restrict__ gg,
                      const float* __restrict__ bb, float* __restrict__ x1) {
  int c = blockIdx.x, t = threadIdx.x;
  float v = (t < N) ? h1[t * HID + c] : 0.f;
  __shared__ float s1[128], s2[128];
  s1[t] = v; s2[t] = v * v; __syncthreads();
  for (int s = 64; s > 0; s >>= 1) { if (t < s) { s1[t] += s1[t + s]; s2[t] += s2[t + s]; } __syncthreads(); }
  float mu = s1[0] / (float)N;
  float var = s2[0] / (float)N - mu * mu;
  float inv = rsqrtf(var + 1e-5f);
  if (t < N) x1[t * HID + c] = fmaxf((v - mu) * inv * gg[c] + bb[c], 0.f);
}

// ---- h2 = (adj @ x1) @ conv2_w ; block=row i, 256 thr ----
__global__ void k_enc2(const float* __restrict__ adj, const float* __restrict__ x1,
                       const float* __restrict__ w2, float* __restrict__ h2) {
  int i = blockIdx.x, t = threadIdx.x;
  __shared__ float t2[HID];
  float s = 0.f;
  for (int j = 0; j < N; ++j) s += adj[i * N + j] * x1[j * HID + t];
  t2[t] = s;
  __syncthreads();
  float h = 0.f;
  for (int k = 0; k < HID; ++k) h += t2[k] * w2[k * HID + t];
  h2[i * HID + t] = h;
}

// ---- BN2 then gh = column sums ; block=col c ----
__global__ void k_bn2gh(const float* __restrict__ h2, const float* __restrict__ gg,
                        const float* __restrict__ bb, float* __restrict__ gh) {
  int c = blockIdx.x, t = threadIdx.x;
  float v = (t < N) ? h2[t * HID + c] : 0.f;
  __shared__ float s1[128], s2[128];
  s1[t] = v; s2[t] = v * v; __syncthreads();
  for (int s = 64; s > 0; s >>= 1) { if (t < s) { s1[t] += s1[t + s]; s2[t] += s2[t + s]; } __syncthreads(); }
  float mu = s1[0] / (float)N;
  float var = s2[0] / (float)N - mu * mu;
  float inv = rsqrtf(var + 1e-5f);
  __syncthreads();
  float xv = (t < N) ? ((v - mu) * inv * gg[c] + bb[c]) : 0.f;
  s1[t] = xv; __syncthreads();
  for (int s = 64; s > 0; s >>= 1) { if (t < s) s1[t] += s1[t + s]; __syncthreads(); }
  if (t == 0) gh[c] = s1[0];
}

// ---- VAE (redundant per block) + decoder ; 25 blocks x 256 thr ----
__global__ void k_vaedec(const float* __restrict__ gh,
                         const float* __restrict__ e11w, const float* __restrict__ e11b,
                         const float* __restrict__ e12w, const float* __restrict__ e12b,
                         const float* __restrict__ d1w, const float* __restrict__ d1b,
                         const float* __restrict__ d2w, const float* __restrict__ d2b,
                         const float* __restrict__ eps, float* __restrict__ kl,
                         float* __restrict__ outp, float* __restrict__ outx) {
  int t = threadIdx.x;
  __shared__ float ghs[HID], zs[LAT], h1d[LAT], kr[LAT];
  ghs[t] = gh[t];
  __syncthreads();
  if (t < LAT) {
    float a = e11b[t], c = e12b[t];
    for (int k = 0; k < HID; ++k) {
      float g = ghs[k];
      a = fmaf(e11w[t * HID + k], g, a);
      c = fmaf(e12w[t * HID + k], g, c);
    }
    zs[t] = eps[t] * expf(0.5f * c) + a;
    kr[t] = 1.f + c - a * a - expf(c);
  }
  __syncthreads();
  if (blockIdx.x == 0 && t == 0) {
    float s = 0.f;
    for (int k = 0; k < LAT; ++k) s += kr[k];
    kl[0] = -0.5f * s / (float)(N * N);
  }
  if (t < LAT) {
    float hv = d1b[t];
    for (int k = 0; k < LAT; ++k) hv = fmaf(d1w[t * LAT + k], zs[k], hv);
    h1d[t] = fmaxf(hv, 0.f);
  }
  __syncthreads();
  int o = blockIdx.x * 256 + t;
  if (o < OUTDIM) {
    const float4* wr = (const float4*)(d2w + o * LAT);
    float s = d2b[o];
    for (int k4 = 0; k4 < 32; ++k4) {
      float4 v = wr[k4];
      s = fmaf(v.x, h1d[k4 * 4], fmaf(v.y, h1d[k4 * 4 + 1],
            fmaf(v.z, h1d[k4 * 4 + 2], fmaf(v.w, h1d[k4 * 4 + 3], s))));
    }
    if (o < EDGE) outp[o] = 1.f / (1.f + expf(-s));
    else outx[o - EDGE] = s;
  }
}

// ---- degrees, diagonals, adjacency bitmasks ; block=row a, 128 thr ----
__global__ void k_recon(const float* __restrict__ adj, const float* __restrict__ outp,
                        float* __restrict__ degt, float* __restrict__ degr,
                        float* __restrict__ dt, float* __restrict__ dr,
                        ull* __restrict__ mskg) {
  int a = blockIdx.x, t = threadIdx.x;
  float rv = 0.f, av = 0.f;
  if (t < N) {
    int i2 = min(a, t), j2 = max(a, t);
    rv = outp[triidx(i2, j2)];
    av = adj[a * N + t];
    if (t == a) { dr[a] = rv; dt[a] = av; }
  }
  ull bal = __ballot(t < N && av > 0.5f);
  if ((t & 63) == 0) mskg[a * 2 + (t >> 6)] = bal;
  __shared__ float s1[128], s2[128];
  s1[t] = rv; s2[t] = av; __syncthreads();
  for (int s = 64; s > 0; s >>= 1) { if (t < s) { s1[t] += s1[t + s]; s2[t] += s2[t + s]; } __syncthreads(); }
  if (t == 0) { degr[a] = s1[0]; degt[a] = s2[0]; }
}

// ---- B rows, SdT rows, x0 (both layouts) ; block=row a, 128 thr ----
__global__ void k_simab(const float* __restrict__ outp,
                        const float* __restrict__ degt, const float* __restrict__ degr,
                        const float* __restrict__ dt, const float* __restrict__ dr,
                        float* __restrict__ Bg, float* __restrict__ SdTg,
                        float* __restrict__ x0, float* __restrict__ x0T) {
  int a = blockIdx.x, t = threadIdx.x;
  if (t < N) {
    int i2 = min(a, t), j2 = max(a, t);
    float rv = outp[triidx(i2, j2)];
    Bg[a * N + t] = (t == a) ? 0.f : rv * dr[a] * dr[t];
    SdTg[a * N + t] = dt[t] * dr[a] / (fabsf(degt[t] - degr[a]) + 1.f);
    x0[t * 104 + a] = 1.f / (float)N;
    x0T[a * N + t] = 1.f / (float)N;
  }
}

// ---- one MPM iteration ; block = column a, 128 thr (one row per thread) ----
__global__ __launch_bounds__(128) void k_mpm(
    const float* __restrict__ xin,  const float* __restrict__ xinT,
    float* __restrict__ xout, float* __restrict__ xoutT,
    const float* __restrict__ Bg, const float* __restrict__ SdTg,
    const ull* __restrict__ mskg,
    const float* __restrict__ sspP, float* __restrict__ sspC, int first) {
  const int a = blockIdx.x, t = threadIdx.x;
  const int w = t >> 6, l = t & 63;
  __shared__ __align__(16) float Bs[96];
  __shared__ float Sd[96], Xold[96], Ms[96], Xnew[96];
  __shared__ float red[2], red2[2];
  const bool act = (t < N);
  if (act) {
    Bs[t] = Bg[a * N + t];
    Sd[t] = SdTg[a * N + t];
    Xold[t] = xinT[a * N + t];
  }
  float sv = (!first && act) ? sspP[t] : 0.f;
#pragma unroll
  for (int off = 32; off >= 1; off >>= 1) sv += __shfl_xor(sv, off);
  if (l == 0) red[w] = sv;
  ull w0 = 0, w1 = 0;
  if (act) {
    w0 = mskg[t * 2];
    w1 = mskg[t * 2 + 1];
    if (t < 64) w0 &= ~(1ull << t); else w1 &= ~(1ull << (t - 64));
  }
  __syncthreads();
  const float inv = first ? 1.f : rsqrtf(red[0] + red[1]);
  if (act) {
    const float4* xr = (const float4*)(xin + t * 104);
    const float4* Bs4 = (const float4*)Bs;
    float m0 = 0.f;
#pragma unroll
    for (int k = 0; k < 24; ++k) {
      float4 xq = xr[k];
      float4 bq = Bs4[k];
      m0 = fmaxf(m0, fmaxf(fmaxf(bq.x * xq.x, bq.y * xq.y),
                           fmaxf(bq.z * xq.z, bq.w * xq.w)));
    }
    Ms[t] = m0;
  }
  __syncthreads();
  float ss = 0.f;
  if (act) {
    float macc = 0.f;
    ull mm = w0;
    while (mm) { int j = __builtin_ctzll(mm); mm &= mm - 1; macc += Ms[j]; }
    mm = w1;
    while (mm) { int j = 64 + __builtin_ctzll(mm); mm &= mm - 1; macc += Ms[j]; }
    float v = fmaf(Xold[t], Sd[t], macc) * inv;
    Xnew[t] = v;
    xout[t * 104 + a] = v;
    ss = v * v;
  }
#pragma unroll
  for (int off = 32; off >= 1; off >>= 1) ss += __shfl_xor(ss, off);
  if (l == 0) red2[w] = ss;
  __syncthreads();
  if (t == 0) sspC[a] = red2[0] + red2[1];
  if (t < 24) {
    float4 q = *(const float4*)&Xnew[4 * t];
    *(float4*)&xoutT[a * N + 4 * t] = q;
  }
}

// ---- greedy (parallel incremental row-max) + losses ; 1 block x 128 thr ----
__global__ __launch_bounds__(128) void k_fin(
    const float* __restrict__ xfin,      // [96][104] row-major
    const float* __restrict__ adj, const float* __restrict__ feats,
    const float* __restrict__ outp, const float* __restrict__ outx,
    const float* __restrict__ kl, float* __restrict__ out) {
  int t = threadIdx.x;
  int w = t >> 6, l = t & 63;
  __shared__ float X[96 * 100];
  __shared__ int INDS[96];
  __shared__ ull kw[2];
  __shared__ float rf[2], rb[2];
  for (int e = t; e < 96 * 26; e += 128) {     // 2496 float4 slots = 96 rows x 26
    int i = e / 26, q = e - i * 26;
    if (q < 24) {
      float4 v = *(const float4*)&xfin[i * 104 + 4 * q];
      *(float4*)&X[i * 100 + 4 * q] = v;
    }
  }
  __syncthreads();

  // per-row incremental max: thread t owns row t
  bool alive = (t < N);
  float mA = -1.f; int aA = 0;
  if (alive) {
    const float4* xr4 = (const float4*)&X[t * 100];
#pragma unroll
    for (int q = 0; q < 24; ++q) {
      float4 v = xr4[q];
      if (v.x > mA) { mA = v.x; aA = 4 * q; }
      if (v.y > mA) { mA = v.y; aA = 4 * q + 1; }
      if (v.z > mA) { mA = v.z; aA = 4 * q + 2; }
      if (v.w > mA) { mA = v.w; aA = 4 * q + 3; }
    }
  }

  for (int step = 0; step < N; ++step) {
    ull key = alive ? ((((ull)__float_as_uint(mA)) << 32) |
                       (unsigned)(0x3FFF - (t * N + aA))) : 0ull;
#pragma unroll
    for (int off = 1; off < 64; off <<= 1) {
      ull o = __shfl_xor(key, off);
      if (o > key) key = o;
    }
    if (l == 0) kw[w] = key;
    __syncthreads();
    ull kk = kw[0] > kw[1] ? kw[0] : kw[1];
    int flat = 0x3FFF - (int)(kk & 0xFFFFFFFFull);
    int r = flat / N, c = flat - (flat / N) * N;
    if (t == 0) INDS[c] = r;
    if (t == r) alive = false;
    if (t < N) X[t * 100 + c] = -FLT_MAX;      // own-row write, no hazard
    if (alive && aA == c) {                    // rescan own row (parallel, pipelined)
      mA = -1.f; aA = 0;
      const float4* xr4 = (const float4*)&X[t * 100];
#pragma unroll
      for (int q = 0; q < 24; ++q) {
        float4 v = xr4[q];
        if (v.x > mA) { mA = v.x; aA = 4 * q; }
        if (v.y > mA) { mA = v.y; aA = 4 * q + 1; }
        if (v.z > mA) { mA = v.z; aA = 4 * q + 2; }
        if (v.w > mA) { mA = v.w; aA = 4 * q + 3; }
      }
    }
    __syncthreads();
  }

  // ---- losses ----
  float accf = 0.f;
  for (int p = t; p < N * DIN; p += 128) {
    int i = p >> 4, k = p & 15;
    float d = outx[p] - feats[INDS[i] * DIN + k];
    accf += d * d;
  }
  float accb = 0.f;
  for (int i = 0; i < N; ++i) {
    int basee = triidx(i, i);
    int rowlen = N - i;
    for (int jq = t; jq < rowlen; jq += 128) {
      int j = i + jq;
      float tv = adj[INDS[i] * N + INDS[j]];
      float pr = outp[basee + jq];
      float l1 = fmaxf(logf(pr), -100.f);
      float l0 = fmaxf(log1pf(-pr), -100.f);
      accb += tv * l1 + (1.f - tv) * l0;
    }
  }
#pragma unroll
  for (int off = 32; off >= 1; off >>= 1) { accf += __shfl_xor(accf, off); accb += __shfl_xor(accb, off); }
  if (l == 0) { rf[w] = accf; rb[w] = accb; }
  __syncthreads();
  if (t == 0) {
    float ff = rf[0] + rf[1];
    float bb = rb[0] + rb[1];
    out[0] = (-bb / (float)EDGE) + kl[0] + ff / (float)(N * DIN);
  }
}

extern "C" void kernel_launch(void* const* d_in, const int* in_sizes, int n_in,
                              void* d_out, int out_size, void* d_ws, size_t ws_size,
                              hipStream_t stream) {
  const float* feats = (const float*)d_in[0];
  const float* adj   = (const float*)d_in[1];
  const float* w1    = (const float*)d_in[2];
  const float* w2    = (const float*)d_in[3];
  const float* bn1g  = (const float*)d_in[4];
  const float* bn1b  = (const float*)d_in[5];
  const float* bn2g  = (const float*)d_in[6];
  const float* bn2b  = (const float*)d_in[7];
  const float* e11w  = (const float*)d_in[8];
  const float* e11b  = (const float*)d_in[9];
  const float* e12w  = (const float*)d_in[10];
  const float* e12b  = (const float*)d_in[11];
  const float* d1w   = (const float*)d_in[12];
  const float* d1b   = (const float*)d_in[13];
  const float* d2w   = (const float*)d_in[14];
  const float* d2b   = (const float*)d_in[15];
  const float* eps   = (const float*)d_in[16];

  float* ws   = (float*)d_ws;
  float* h1   = ws + WH1;
  float* x1   = ws + WX1;
  float* h2   = ws + WH2;
  float* gh   = ws + WGH;
  float* kl   = ws + WKL;
  float* outp = ws + WOUTP;
  float* outx = ws + WOUTX;
  float* degt = ws + WDEGT;
  float* degr = ws + WDEGR;
  float* dt   = ws + WDT;
  float* dr   = ws + WDR;
  float* Bg   = ws + WB;
  float* SdTg = ws + WSDT;
  ull*   mskg = (ull*)(ws + WMSK);
  float* xa   = ws + WXA;
  float* xb   = ws + WXB;
  float* xaT  = ws + WXAT;
  float* xbT  = ws + WXBT;
  float* ssp  = ws + WSSP;
  float* out  = (float*)d_out;

  k_enc1<<<96, 256, 0, stream>>>(adj, feats, w1, h1);
  k_bn1<<<256, 128, 0, stream>>>(h1, bn1g, bn1b, x1);
  k_enc2<<<96, 256, 0, stream>>>(adj, x1, w2, h2);
  k_bn2gh<<<256, 128, 0, stream>>>(h2, bn2g, bn2b, gh);
  k_vaedec<<<25, 256, 0, stream>>>(gh, e11w, e11b, e12w, e12b, d1w, d1b,
                                   d2w, d2b, eps, kl, outp, outx);
  k_recon<<<96, 128, 0, stream>>>(adj, outp, degt, degr, dt, dr, mskg);
  k_simab<<<96, 128, 0, stream>>>(outp, degt, degr, dt, dr, Bg, SdTg, xa, xaT);

  for (int m = 0; m < 50; ++m) {
    const float* xi  = (m & 1) ? xb : xa;
    const float* xiT = (m & 1) ? xbT : xaT;
    float* xo        = (m & 1) ? xa : xb;
    float* xoT       = (m & 1) ? xaT : xbT;
    float* sc        = ssp + (m & 1) * N;
    const float* sp  = ssp + ((m & 1) ^ 1) * N;
    k_mpm<<<96, 128, 0, stream>>>(xi, xiT, xo, xoT, Bg, SdTg, mskg, sp, sc,
                                  (m == 0) ? 1 : 0);
  }
  // m=49 odd -> final x in xa
  k_fin<<<1, 128, 0, stream>>>(xa, adj, feats, outp, outx, kl, out);
}